// Round 2
// baseline (108.935 us; speedup 1.0000x reference)
//
#include <hip/hip_runtime.h>
#include <stdint.h>
#include <math.h>

// Must match numpy's unfused fp32 ops exactly: no FMA contraction in this TU.
#pragma clang fp contract(off)

#define N        8192
#define NCHUNK   128      // N / 64
#define NTILE    64       // 128-box tiles
#define MAX_OUT  300
#define BLIM     32       // pruned mask: chunks [0,32) both dims (rows/cols < 2048)
#define TLIM     14       // scan-try tiles: all accesses stay < BLIM chunks

// ---------------------------------------------------------------------------
// Phase 1a: partial rank counts, atomic-free. Block (bi,bj) writes its own
// slice rank32[bj][i]; scatter sums the 32 partials. Comparator: score desc,
// idx asc (unique keys -> ranks form a permutation).
// ---------------------------------------------------------------------------
__global__ void nms_rank_partial(const float* __restrict__ scores,
                                 int* __restrict__ rank32) {
    __shared__ uint32_t sk[256];
    const int tid = threadIdx.x;
    const int bi  = blockIdx.y, bj = blockIdx.x;
    const int jbase = bj * 256;

    sk[tid] = __float_as_uint(scores[jbase + tid]);  // scores >= 0 -> uint-monotonic
    __syncthreads();

    const int i = bi * 256 + tid;
    const uint32_t my = __float_as_uint(scores[i]);

    int cnt = 0;
    const uint4* sk4 = (const uint4*)sk;
    for (int jj = 0; jj < 64; ++jj) {          // 64 x b128 LDS broadcast reads
        uint4 v = sk4[jj];
        int j0 = jbase + jj * 4;
        cnt += (v.x > my) || (v.x == my && (j0 + 0) < i);
        cnt += (v.y > my) || (v.y == my && (j0 + 1) < i);
        cnt += (v.z > my) || (v.z == my && (j0 + 2) < i);
        cnt += (v.w > my) || (v.w == my && (j0 + 3) < i);
    }
    rank32[bj * N + i] = cnt;
}

// ---------------------------------------------------------------------------
// Phase 1b: sum partials, scatter boxes/indices into score-sorted order.
// ---------------------------------------------------------------------------
__global__ void nms_scatter(const float4* __restrict__ rois,
                            const int*    __restrict__ rank32,
                            float4* __restrict__ sboxes,
                            int*    __restrict__ sidx) {
    const int i = blockIdx.x * blockDim.x + threadIdx.x;
    int r = 0;
#pragma unroll
    for (int k = 0; k < 32; ++k) r += rank32[k * N + i];
    sboxes[r] = rois[i];
    sidx[r]   = i;
}

// ---------------------------------------------------------------------------
// IoU suppression word for one (row-tile, col-lane) pair set.
// Exact f64 compare == fp32 IEEE div vs 0.5 (verified bit-exact R4/R5).
// ---------------------------------------------------------------------------
__device__ __forceinline__ uint64_t iou_word(const float4 cb, const float ac,
                                             const float4* __restrict__ rb,
                                             const float*  __restrict__ ra,
                                             const bool diag, const int lane) {
    uint64_t myword = 0;
    for (int r = 0; r < 64; ++r) {
        const float4 b  = rb[r];           // LDS broadcast
        const float  ar = ra[r];
        float lx    = fmaxf(b.x, cb.x);
        float ly    = fmaxf(b.y, cb.y);
        float hx    = fminf(b.z, cb.z);
        float hy    = fminf(b.w, cb.w);
        float w     = fmaxf(hx - lx, 0.0f);
        float h     = fmaxf(hy - ly, 0.0f);
        float inter = w * h;
        float denom = (ar + ac) - inter;   // left-to-right like numpy
        double di = (double)inter, dd = (double)denom;
        bool sup = (di + di) > (dd + dd * 0x1p-24);  // exact: fl32(di/dd) > 0.5
        uint64_t word = __ballot(sup);
        if (diag)                          // keep only cols > r (wave-uniform)
            word &= (r == 63) ? 0ull : (~0ull << (r + 1));
        myword = (lane == r) ? word : myword;
    }
    return myword;
}

// ---------------------------------------------------------------------------
// Phase 2a: PRUNED suppression mask — only chunks bi,bj < BLIM (upper tri).
// 528 blocks instead of 8256: the scan terminates at ~tile 3-5 for this
// distribution, so rows/cols beyond chunk ~15 are never consumed.
// ---------------------------------------------------------------------------
__global__ void __launch_bounds__(64)
nms_mask_pruned(const float4* __restrict__ sboxes,
                uint64_t* __restrict__ maskT) {
    // decode linear block -> (bi,bj), bj >= bi  (528 = 32*33/2 blocks)
    const int L = blockIdx.x;
    int bi = (int)(32.5 - sqrt(1056.25 - 2.0 * (double)L));
    if (bi < 0) bi = 0;
    if (bi > 31) bi = 31;
    while (bi < 31 && (bi + 1) * 32 - ((bi + 1) * bi) / 2 <= L) ++bi;
    while (bi > 0 && bi * 32 - (bi * (bi - 1)) / 2 > L) --bi;
    const int bj = bi + (L - (bi * 32 - (bi * (bi - 1)) / 2));

    const int lane = threadIdx.x;          // 0..63 = column within chunk bj
    const float4 cb = sboxes[bj * 64 + lane];
    const float  ac = (cb.z - cb.x) * (cb.w - cb.y);

    __shared__ float4 rb[64];
    __shared__ float  ra[64];
    {
        float4 t = sboxes[bi * 64 + lane];
        rb[lane] = t;
        ra[lane] = (t.z - t.x) * (t.w - t.y);
    }
    __syncthreads();

    uint64_t myword = iou_word(cb, ac, rb, ra, bi == bj, lane);
    maskT[(size_t)bj * N + bi * 64 + lane] = myword;   // 512B coalesced store
}

// ---------------------------------------------------------------------------
// Phase 2b (FALLBACK, flag-gated): rest of the mask. Near-free when flag==0.
// Grid (bjq=32, bi=128), 4 waves/block, wave w does bj = bjq*4+w.
// ---------------------------------------------------------------------------
__global__ void __launch_bounds__(256)
nms_mask_rest(const float4* __restrict__ sboxes,
              uint64_t* __restrict__ maskT,
              const int* __restrict__ flag) {
    if (flag[0] == 0) return;              // scan-try completed: nothing to do
    const int bi  = blockIdx.y;            // 0..127 (row chunk)
    const int bjq = blockIdx.x;            // 0..31  (col chunk group of 4)
    const int w    = threadIdx.x >> 6;
    const int lane = threadIdx.x & 63;
    const int bj   = bjq * 4 + w;

    __shared__ float4 rb[64];
    __shared__ float  ra[64];
    if (threadIdx.x < 64) {
        float4 t = sboxes[bi * 64 + threadIdx.x];
        rb[threadIdx.x] = t;
        ra[threadIdx.x] = (t.z - t.x) * (t.w - t.y);
    }
    __syncthreads();

    if (bj < bi) return;                   // lower triangle unused
    if (bi < BLIM && bj < BLIM) return;    // already written by pruned kernel

    const float4 cb = sboxes[bj * 64 + lane];
    const float  ac = (cb.z - cb.x) * (cb.w - cb.y);
    uint64_t myword = iou_word(cb, ac, rb, ra, bi == bj, lane);
    maskT[(size_t)bj * N + bi * 64 + lane] = myword;
}

// ---------------------------------------------------------------------------
// Wave-wide 64-bit OR butterfly (all lanes get the reduction).
// ---------------------------------------------------------------------------
__device__ __forceinline__ uint64_t shflx64(uint64_t v, int m) {
    uint32_t lo = (uint32_t)__shfl_xor((unsigned int)(v & 0xffffffffull), m, 64);
    uint32_t hi = (uint32_t)__shfl_xor((unsigned int)(v >> 32), m, 64);
    return ((uint64_t)hi << 32) | lo;
}
__device__ __forceinline__ uint64_t wave_or64(uint64_t v) {
#pragma unroll
    for (int m = 1; m < 64; m <<= 1) v |= shflx64(v, m);
    return v;
}

// ---------------------------------------------------------------------------
// Greedy kernel (NMS keep-set) of a 64-box chunk via fixed-point iteration.
// D[lane] = suppression word of row `lane` (forward edges only: cols > lane
// for diagonal tiles). cand = candidates not yet removed. The greedy keep set
// K is the unique DAG kernel: K = cand \ N_out(K). Iterating
// k_{j+1} = cand \ N_out(k_j) brackets K (evens shrink, odds grow) and
// converges in <= chain-depth+2 <= 66 iterations; sparse data converges in
// 2-3. Replaces the serial per-box ctz+readlane chain (~100+ cyc/box).
// ---------------------------------------------------------------------------
__device__ __forceinline__ uint64_t resolve_chunk(uint64_t D, uint64_t cand,
                                                  int lane) {
    uint64_t kept = cand;
    for (int itr = 0; itr < 66; ++itr) {
        uint64_t contrib = ((kept >> lane) & 1) ? D : 0ull;
        uint64_t S = wave_or64(contrib);        // N_out(kept)
        uint64_t nk = cand & ~S;
        if (nk == kept) break;                  // fixed point = greedy kernel
        kept = nk;
    }
    return kept;
}

// ---------------------------------------------------------------------------
// Phase 3: pipelined greedy scan, LAZY application + fixed-point resolve.
//  wave 0 : resolve tile it (fixed-point, wave-parallel) + fold tile it's
//           kept rows into chunks 2it+2, 2it+3 (masked wave-OR reduces).
//  wave 1 : prefetch tile it+1 words (D0,D1,X,Y0a,Y0b,Y1a,Y1b) into LDS dbuf.
//  waves 2-15 : apply ALL kept rows from tiles <= it-1 to EXACTLY the two
//           chunks 2it+2, 2it+3 (one 8B gather per thread).
//  TRYMODE: run TLIM tiles against the pruned mask; write flag=1 if the scan
//           did not reach MAX_OUT kept (fallback path re-runs everything).
// ---------------------------------------------------------------------------
template<bool TRYMODE>
__global__ void __launch_bounds__(1024)
nms_scan_k(const uint64_t* __restrict__ maskT,
           const int*      __restrict__ sidx,
           int*            __restrict__ out,
           int*            __restrict__ flag) {
    __shared__ uint32_t removed32[2 * NCHUNK];   // per-chunk removed, lo/hi pairs
    __shared__ uint64_t pf[2][7][64];            // dbuf: D0,D1,X,Y0a,Y0b,Y1a,Y1b
    __shared__ uint64_t s_kmask[NCHUNK];
    __shared__ int      s_kbase[NCHUNK];
    __shared__ int      s_klist[448];            // cumulative kept rows (<=427)
    __shared__ int      s_ksnap[2];              // kept count BEFORE tile, parity dbuf
    __shared__ int      s_kept, s_done, s_nch;

    if (!TRYMODE) {
        if (flag[0] == 0) return;                // try-scan already finished
    }

    const int t    = threadIdx.x;
    const int lane = t & 63;
    const int wave = t >> 6;

    if (t < 2 * NCHUNK) removed32[t] = 0;
    if (t == 0) { s_kept = 0; s_done = 0; s_nch = 0; s_ksnap[0] = 0; s_ksnap[1] = 0; }
    if (wave == 1) {                             // prefetch tile 0 into pf[0]
        pf[0][0][lane] = maskT[(size_t)0 * N + 0 * 64 + lane];   // D0 (diag c0)
        pf[0][1][lane] = maskT[(size_t)1 * N + 1 * 64 + lane];   // D1 (diag c1)
        pf[0][2][lane] = maskT[(size_t)1 * N + 0 * 64 + lane];   // X  (c0 rows @ c1)
        pf[0][3][lane] = maskT[(size_t)2 * N + 0 * 64 + lane];   // Y0a (c0 rows @ col2)
        pf[0][4][lane] = maskT[(size_t)2 * N + 1 * 64 + lane];   // Y0b (c1 rows @ col2)
        pf[0][5][lane] = maskT[(size_t)3 * N + 0 * 64 + lane];   // Y1a (c0 rows @ col3)
        pf[0][6][lane] = maskT[(size_t)3 * N + 1 * 64 + lane];   // Y1b (c1 rows @ col3)
    }
    __syncthreads();

    const int TEND = TRYMODE ? TLIM : NTILE;
    for (int it = 0; it < TEND; ++it) {
        const int c0 = 2 * it, c1 = 2 * it + 1;
        const int buf = it & 1;

        if (wave == 0) {
            // ---- A: resolve tile it (fixed-point, no serial readlane chain) ----
            uint64_t D0  = pf[buf][0][lane], D1  = pf[buf][1][lane];
            uint64_t X   = pf[buf][2][lane];
            uint64_t Y0a = pf[buf][3][lane], Y0b = pf[buf][4][lane];
            uint64_t Y1a = pf[buf][5][lane], Y1b = pf[buf][6][lane];
            uint64_t rem0 = (uint64_t)removed32[2 * c0] | ((uint64_t)removed32[2 * c0 + 1] << 32);
            uint64_t rem1 = (uint64_t)removed32[2 * c1] | ((uint64_t)removed32[2 * c1 + 1] << 32);

            // chunk c0: greedy kernel + cross-chunk folds via masked reduces
            uint64_t keep0 = resolve_chunk(D0, ~rem0, lane);
            uint64_t m0 = ((keep0 >> lane) & 1) ? ~0ull : 0ull;
            uint64_t xw = wave_or64(X   & m0);
            uint64_t y0 = wave_or64(Y0a & m0);
            uint64_t y1 = wave_or64(Y1a & m0);

            // chunk c1
            rem1 |= xw;
            uint64_t keep1 = resolve_chunk(D1, ~rem1, lane);
            uint64_t m1 = ((keep1 >> lane) & 1) ? ~0ull : 0ull;
            y0 |= wave_or64(Y0b & m1);
            y1 |= wave_or64(Y1b & m1);

            // fold THIS tile's kept into the next two chunks (lazy-B covers
            // all earlier tiles' kept for those same chunks)
            if (c0 + 2 < NCHUNK && y0) {
                atomicOr(&removed32[2 * (c0 + 2)],     (uint32_t)y0);
                atomicOr(&removed32[2 * (c0 + 2) + 1], (uint32_t)(y0 >> 32));
            }
            if (c0 + 3 < NCHUNK && y1) {
                atomicOr(&removed32[2 * (c0 + 3)],     (uint32_t)y1);
                atomicOr(&removed32[2 * (c0 + 3) + 1], (uint32_t)(y1 >> 32));
            }
            const int n0 = __popcll(keep0), n1 = __popcll(keep1);
            const int base = s_kept;               // uniform read (write below is later)
            if ((keep0 >> lane) & 1) {
                int p = __popcll(keep0 & ((1ull << lane) - 1ull));
                s_klist[base + p] = c0 * 64 + lane;
            }
            if ((keep1 >> lane) & 1) {
                int p = n0 + __popcll(keep1 & ((1ull << lane) - 1ull));
                s_klist[base + p] = c1 * 64 + lane;
            }
            if (lane == 0) {
                s_kmask[c0] = keep0;  s_kmask[c1] = keep1;
                s_kbase[c0] = base;   s_kbase[c1] = base + n0;
                int nk      = base + n0 + n1;
                s_kept      = nk;
                s_ksnap[(it + 1) & 1] = nk;        // snapshot for B @ tile it+1
                s_nch       = c1 + 1;
                if (TRYMODE) {
                    if (nk >= MAX_OUT) s_done = 1;
                } else {
                    if (nk >= MAX_OUT || it == NTILE - 1) s_done = 1;
                }
            }
        } else if (wave == 1) {
            // ---- prefetch tile it+1 into pf[buf^1] ----
            const int p0 = 2 * it + 2, p1 = 2 * it + 3;
            const int m0 = 2 * it + 4, m1 = 2 * it + 5;
            if (p0 < NCHUNK) {
                pf[buf ^ 1][0][lane] = maskT[(size_t)p0 * N + p0 * 64 + lane];
                pf[buf ^ 1][1][lane] = maskT[(size_t)p1 * N + p1 * 64 + lane];
                pf[buf ^ 1][2][lane] = maskT[(size_t)p1 * N + p0 * 64 + lane];
                if (m0 < NCHUNK) {
                    pf[buf ^ 1][3][lane] = maskT[(size_t)m0 * N + p0 * 64 + lane];
                    pf[buf ^ 1][4][lane] = maskT[(size_t)m0 * N + p1 * 64 + lane];
                    pf[buf ^ 1][5][lane] = maskT[(size_t)m1 * N + p0 * 64 + lane];
                    pf[buf ^ 1][6][lane] = maskT[(size_t)m1 * N + p1 * 64 + lane];
                }
            }
        } else {
            // ---- lazy B: apply ALL kept rows (tiles <= it-1) to the two
            //      chunks consumed after the next tile: 2it+2, 2it+3 ----
            if (it >= 1) {
                const int kprev = s_ksnap[it & 1]; // kept count before tile it
                const int col   = c0 + 2 + (wave & 1);
                const int idx   = ((wave - 2) >> 1) * 64 + lane;   // 0..447
                uint64_t v = 0;
                if (idx < kprev && col < NCHUNK)
                    v = maskT[(size_t)col * N + s_klist[idx]];
                // wave-wide OR reduce (whole wave has the same col)
                v = wave_or64(v);
                if (lane == 0 && v != 0 && col < NCHUNK) {
                    atomicOr(&removed32[2 * col],     (uint32_t)v);
                    atomicOr(&removed32[2 * col + 1], (uint32_t)(v >> 32));
                }
            }
        }
        __syncthreads();
        if (s_done) break;
    }

    if (TRYMODE) {
        if (t == 0) flag[0] = s_done ? 0 : 1;
        if (!s_done) return;                     // fallback pass will finish
    }

    // ---- parallel output pass ----
    const int nch = s_nch;
    for (int cp = t >> 6; cp < nch; cp += 16) {
        uint64_t km = s_kmask[cp];
        if ((km >> lane) & 1) {
            int pos = s_kbase[cp] + __popcll(km & ((1ull << lane) - 1ull));
            if (pos < MAX_OUT) out[pos] = sidx[cp * 64 + lane];
        }
    }
    const int start = s_kept < MAX_OUT ? s_kept : MAX_OUT;
    for (int p = start + t; p < MAX_OUT; p += 1024) out[p] = -1;
}

// ---------------------------------------------------------------------------
extern "C" void kernel_launch(void* const* d_in, const int* in_sizes, int n_in,
                              void* d_out, int out_size, void* d_ws, size_t ws_size,
                              hipStream_t stream) {
    const float4* rois   = (const float4*)d_in[0];   // [8192,4] fp32
    const float*  scores = (const float*)d_in[1];    // [8192]   fp32
    int* out = (int*)d_out;                          // [300] int32

    // workspace layout (~9.3 MB + flag)
    float4*   sboxes = (float4*)d_ws;                                      // 128 KiB
    int*      sidx   = (int*)((char*)d_ws + 128 * 1024);                   //  32 KiB
    uint64_t* maskT  = (uint64_t*)((char*)d_ws + 160 * 1024);              //   8 MiB
    int*      rank32 = (int*)((char*)d_ws + 160 * 1024 + 8 * 1024 * 1024); //   1 MiB
    int*      flag   = (int*)((char*)d_ws + 160 * 1024 + 9 * 1024 * 1024); //   4 B

    nms_rank_partial<<<dim3(32, 32), dim3(256), 0, stream>>>(scores, rank32);
    nms_scatter<<<dim3(32), dim3(256), 0, stream>>>(rois, rank32, sboxes, sidx);
    nms_mask_pruned<<<dim3(528), dim3(64), 0, stream>>>(sboxes, maskT);
    nms_scan_k<true><<<dim3(1), dim3(1024), 0, stream>>>(maskT, sidx, out, flag);
    // Fallback chain: near-null dispatches when the try-scan completed.
    nms_mask_rest<<<dim3(32, 128), dim3(256), 0, stream>>>(sboxes, maskT, flag);
    nms_scan_k<false><<<dim3(1), dim3(1024), 0, stream>>>(maskT, sidx, out, flag);
}

// Round 3
// 85.130 us; speedup vs baseline: 1.2796x; 1.2796x over previous
//
#include <hip/hip_runtime.h>
#include <stdint.h>
#include <math.h>

// Must match numpy's unfused fp32 ops exactly: no FMA contraction in this TU.
#pragma clang fp contract(off)

#define N        8192
#define NCHUNK   128      // N / 64
#define NTILE    64       // 128-box tiles
#define MAX_OUT  300
#define BLIM     32       // pruned mask: chunks [0,32) both dims (rows/cols < 2048)
#define TLIM     14       // scan-try tiles: all accesses stay < BLIM chunks

// ---------------------------------------------------------------------------
// Phase 1a: partial rank counts, atomic-free. Block (bi,bj) writes its own
// slice rank32[bj][i]; scatter sums the 32 partials. Comparator: score desc,
// idx asc (unique keys -> ranks form a permutation).
// ---------------------------------------------------------------------------
__global__ void nms_rank_partial(const float* __restrict__ scores,
                                 int* __restrict__ rank32) {
    __shared__ uint32_t sk[256];
    const int tid = threadIdx.x;
    const int bi  = blockIdx.y, bj = blockIdx.x;
    const int jbase = bj * 256;

    sk[tid] = __float_as_uint(scores[jbase + tid]);  // scores >= 0 -> uint-monotonic
    __syncthreads();

    const int i = bi * 256 + tid;
    const uint32_t my = __float_as_uint(scores[i]);

    int cnt = 0;
    const uint4* sk4 = (const uint4*)sk;
    for (int jj = 0; jj < 64; ++jj) {          // 64 x b128 LDS broadcast reads
        uint4 v = sk4[jj];
        int j0 = jbase + jj * 4;
        cnt += (v.x > my) || (v.x == my && (j0 + 0) < i);
        cnt += (v.y > my) || (v.y == my && (j0 + 1) < i);
        cnt += (v.z > my) || (v.z == my && (j0 + 2) < i);
        cnt += (v.w > my) || (v.w == my && (j0 + 3) < i);
    }
    rank32[bj * N + i] = cnt;
}

// ---------------------------------------------------------------------------
// Phase 1b: sum partials, scatter boxes/indices into score-sorted order.
// ---------------------------------------------------------------------------
__global__ void nms_scatter(const float4* __restrict__ rois,
                            const int*    __restrict__ rank32,
                            float4* __restrict__ sboxes,
                            int*    __restrict__ sidx) {
    const int i = blockIdx.x * blockDim.x + threadIdx.x;
    int r = 0;
#pragma unroll
    for (int k = 0; k < 32; ++k) r += rank32[k * N + i];
    sboxes[r] = rois[i];
    sidx[r]   = i;
}

// ---------------------------------------------------------------------------
// IoU suppression word for one (row-tile, col-lane) pair set.
// Exact f64 compare == fp32 IEEE div vs 0.5 (verified bit-exact R4/R5).
// ---------------------------------------------------------------------------
__device__ __forceinline__ uint64_t iou_word(const float4 cb, const float ac,
                                             const float4* __restrict__ rb,
                                             const float*  __restrict__ ra,
                                             const bool diag, const int lane) {
    uint64_t myword = 0;
    for (int r = 0; r < 64; ++r) {
        const float4 b  = rb[r];           // LDS broadcast
        const float  ar = ra[r];
        float lx    = fmaxf(b.x, cb.x);
        float ly    = fmaxf(b.y, cb.y);
        float hx    = fminf(b.z, cb.z);
        float hy    = fminf(b.w, cb.w);
        float w     = fmaxf(hx - lx, 0.0f);
        float h     = fmaxf(hy - ly, 0.0f);
        float inter = w * h;
        float denom = (ar + ac) - inter;   // left-to-right like numpy
        double di = (double)inter, dd = (double)denom;
        bool sup = (di + di) > (dd + dd * 0x1p-24);  // exact: fl32(di/dd) > 0.5
        uint64_t word = __ballot(sup);
        if (diag)                          // keep only cols > r (wave-uniform)
            word &= (r == 63) ? 0ull : (~0ull << (r + 1));
        myword = (lane == r) ? word : myword;
    }
    return myword;
}

// ---------------------------------------------------------------------------
// Phase 2a: PRUNED suppression mask — only chunks bi,bj < BLIM (upper tri).
// 528 blocks instead of 8256: the scan terminates at ~tile 3-5 for this
// distribution, so rows/cols beyond chunk ~15 are never consumed.
// ---------------------------------------------------------------------------
__global__ void __launch_bounds__(64)
nms_mask_pruned(const float4* __restrict__ sboxes,
                uint64_t* __restrict__ maskT) {
    // decode linear block -> (bi,bj), bj >= bi  (528 = 32*33/2 blocks)
    const int L = blockIdx.x;
    int bi = (int)(32.5 - sqrt(1056.25 - 2.0 * (double)L));
    if (bi < 0) bi = 0;
    if (bi > 31) bi = 31;
    while (bi < 31 && (bi + 1) * 32 - ((bi + 1) * bi) / 2 <= L) ++bi;
    while (bi > 0 && bi * 32 - (bi * (bi - 1)) / 2 > L) --bi;
    const int bj = bi + (L - (bi * 32 - (bi * (bi - 1)) / 2));

    const int lane = threadIdx.x;          // 0..63 = column within chunk bj
    const float4 cb = sboxes[bj * 64 + lane];
    const float  ac = (cb.z - cb.x) * (cb.w - cb.y);

    __shared__ float4 rb[64];
    __shared__ float  ra[64];
    {
        float4 t = sboxes[bi * 64 + lane];
        rb[lane] = t;
        ra[lane] = (t.z - t.x) * (t.w - t.y);
    }
    __syncthreads();

    uint64_t myword = iou_word(cb, ac, rb, ra, bi == bj, lane);
    maskT[(size_t)bj * N + bi * 64 + lane] = myword;   // 512B coalesced store
}

// ---------------------------------------------------------------------------
// Phase 2b (FALLBACK, flag-gated): rest of the mask. Near-free when flag==0.
// Grid (bjq=32, bi=128), 4 waves/block, wave w does bj = bjq*4+w.
// ---------------------------------------------------------------------------
__global__ void __launch_bounds__(256)
nms_mask_rest(const float4* __restrict__ sboxes,
              uint64_t* __restrict__ maskT,
              const int* __restrict__ flag) {
    if (flag[0] == 0) return;              // scan-try completed: nothing to do
    const int bi  = blockIdx.y;            // 0..127 (row chunk)
    const int bjq = blockIdx.x;            // 0..31  (col chunk group of 4)
    const int w    = threadIdx.x >> 6;
    const int lane = threadIdx.x & 63;
    const int bj   = bjq * 4 + w;

    __shared__ float4 rb[64];
    __shared__ float  ra[64];
    if (threadIdx.x < 64) {
        float4 t = sboxes[bi * 64 + threadIdx.x];
        rb[threadIdx.x] = t;
        ra[threadIdx.x] = (t.z - t.x) * (t.w - t.y);
    }
    __syncthreads();

    if (bj < bi) return;                   // lower triangle unused
    if (bi < BLIM && bj < BLIM) return;    // already written by pruned kernel

    const float4 cb = sboxes[bj * 64 + lane];
    const float  ac = (cb.z - cb.x) * (cb.w - cb.y);
    uint64_t myword = iou_word(cb, ac, rb, ra, bi == bj, lane);
    maskT[(size_t)bj * N + bi * 64 + lane] = myword;
}

// ---------------------------------------------------------------------------
// Wave-wide 64-bit OR butterfly (used only by lazy-B waves, off critical path).
// ---------------------------------------------------------------------------
__device__ __forceinline__ uint64_t shflx64(uint64_t v, int m) {
    uint32_t lo = (uint32_t)__shfl_xor((unsigned int)(v & 0xffffffffull), m, 64);
    uint32_t hi = (uint32_t)__shfl_xor((unsigned int)(v >> 32), m, 64);
    return ((uint64_t)hi << 32) | lo;
}
__device__ __forceinline__ uint64_t wave_or64(uint64_t v) {
#pragma unroll
    for (int m = 1; m < 64; m <<= 1) v |= shflx64(v, m);
    return v;
}

__device__ __forceinline__ uint64_t rl64(uint64_t v, int l) {
    uint32_t lo = (uint32_t)__builtin_amdgcn_readlane((int)(uint32_t)v, l);
    uint32_t hi = (uint32_t)__builtin_amdgcn_readlane((int)(uint32_t)(v >> 32), l);
    return ((uint64_t)hi << 32) | lo;
}

// ---------------------------------------------------------------------------
// Phase 3: pipelined greedy scan, LAZY application + SPARSITY-PRUNED chain.
//  wave 0 : resolve tile it. Greedy order only matters for boxes that
//           suppress something: chain iterates work = cand & ballot(D!=0)
//           (~3-6 boxes/chunk here, 2 readlanes each), exact greedy.
//           Cross-chunk folds: second sparse loop over kept rows with
//           nonzero X/Y words (6 readlanes each). No butterflies here.
//  wave 1 : prefetch tile it+1 words (D0,D1,X,Y0a,Y0b,Y1a,Y1b) into LDS dbuf.
//  waves 2-15 : apply ALL kept rows from tiles <= it-1 to EXACTLY the two
//           chunks 2it+2, 2it+3 (one 8B gather per thread).
//  TRYMODE: run TLIM tiles against the pruned mask; write flag=1 if the scan
//           did not reach MAX_OUT kept (fallback path re-runs everything).
// ---------------------------------------------------------------------------
template<bool TRYMODE>
__global__ void __launch_bounds__(1024)
nms_scan_k(const uint64_t* __restrict__ maskT,
           const int*      __restrict__ sidx,
           int*            __restrict__ out,
           int*            __restrict__ flag) {
    __shared__ uint32_t removed32[2 * NCHUNK];   // per-chunk removed, lo/hi pairs
    __shared__ uint64_t pf[2][7][64];            // dbuf: D0,D1,X,Y0a,Y0b,Y1a,Y1b
    __shared__ uint64_t s_kmask[NCHUNK];
    __shared__ int      s_kbase[NCHUNK];
    __shared__ int      s_klist[448];            // cumulative kept rows (<=427)
    __shared__ int      s_ksnap[2];              // kept count BEFORE tile, parity dbuf
    __shared__ int      s_kept, s_done, s_nch;

    if (!TRYMODE) {
        if (flag[0] == 0) return;                // try-scan already finished
    }

    const int t    = threadIdx.x;
    const int lane = t & 63;
    const int wave = t >> 6;

    if (t < 2 * NCHUNK) removed32[t] = 0;
    if (t == 0) { s_kept = 0; s_done = 0; s_nch = 0; s_ksnap[0] = 0; s_ksnap[1] = 0; }
    if (wave == 1) {                             // prefetch tile 0 into pf[0]
        pf[0][0][lane] = maskT[(size_t)0 * N + 0 * 64 + lane];   // D0 (diag c0)
        pf[0][1][lane] = maskT[(size_t)1 * N + 1 * 64 + lane];   // D1 (diag c1)
        pf[0][2][lane] = maskT[(size_t)1 * N + 0 * 64 + lane];   // X  (c0 rows @ c1)
        pf[0][3][lane] = maskT[(size_t)2 * N + 0 * 64 + lane];   // Y0a (c0 rows @ col2)
        pf[0][4][lane] = maskT[(size_t)2 * N + 1 * 64 + lane];   // Y0b (c1 rows @ col2)
        pf[0][5][lane] = maskT[(size_t)3 * N + 0 * 64 + lane];   // Y1a (c0 rows @ col3)
        pf[0][6][lane] = maskT[(size_t)3 * N + 1 * 64 + lane];   // Y1b (c1 rows @ col3)
    }
    __syncthreads();

    const int TEND = TRYMODE ? TLIM : NTILE;
    for (int it = 0; it < TEND; ++it) {
        const int c0 = 2 * it, c1 = 2 * it + 1;
        const int buf = it & 1;

        if (wave == 0) {
            // ---- A: resolve tile it (sparsity-pruned serial chain) ----
            uint64_t D0  = pf[buf][0][lane], D1  = pf[buf][1][lane];
            uint64_t X   = pf[buf][2][lane];
            uint64_t Y0a = pf[buf][3][lane], Y0b = pf[buf][4][lane];
            uint64_t Y1a = pf[buf][5][lane], Y1b = pf[buf][6][lane];
            uint64_t rem0 = (uint64_t)removed32[2 * c0] | ((uint64_t)removed32[2 * c0 + 1] << 32);
            uint64_t rem1 = (uint64_t)removed32[2 * c1] | ((uint64_t)removed32[2 * c1 + 1] << 32);

            // chunk c0: only rows with D!=0 can change the suppressed set
            uint64_t nz0  = __ballot(D0 != 0ull);
            uint64_t kill = 0, work = (~rem0) & nz0;
            while (work) {
                int l = __builtin_ctzll(work);
                work &= work - 1;
                if (!(((rem0 | kill) >> l) & 1)) {
                    kill |= rl64(D0, l);
                    work &= ~kill;             // suppressed entries can't fire
                }
            }
            const uint64_t keep0 = ~(rem0 | kill);

            // c0 folds: only kept rows with nonzero X/Y words fire
            uint64_t xw = 0, y0 = 0, y1 = 0;
            {
                uint64_t fnz = __ballot((X | Y0a | Y1a) != 0ull);
                uint64_t fw  = keep0 & fnz;
                while (fw) {
                    int l = __builtin_ctzll(fw);
                    fw &= fw - 1;
                    xw |= rl64(X,   l);
                    y0 |= rl64(Y0a, l);
                    y1 |= rl64(Y1a, l);
                }
            }

            // chunk c1
            rem1 |= xw;
            uint64_t nz1 = __ballot(D1 != 0ull);
            kill = 0; work = (~rem1) & nz1;
            while (work) {
                int l = __builtin_ctzll(work);
                work &= work - 1;
                if (!(((rem1 | kill) >> l) & 1)) {
                    kill |= rl64(D1, l);
                    work &= ~kill;
                }
            }
            const uint64_t keep1 = ~(rem1 | kill);

            // c1 folds
            {
                uint64_t gnz = __ballot((Y0b | Y1b) != 0ull);
                uint64_t gw  = keep1 & gnz;
                while (gw) {
                    int l = __builtin_ctzll(gw);
                    gw &= gw - 1;
                    y0 |= rl64(Y0b, l);
                    y1 |= rl64(Y1b, l);
                }
            }

            // fold THIS tile's kept into the next two chunks (lazy-B covers
            // all earlier tiles' kept for those same chunks)
            if (c0 + 2 < NCHUNK && y0) {
                atomicOr(&removed32[2 * (c0 + 2)],     (uint32_t)y0);
                atomicOr(&removed32[2 * (c0 + 2) + 1], (uint32_t)(y0 >> 32));
            }
            if (c0 + 3 < NCHUNK && y1) {
                atomicOr(&removed32[2 * (c0 + 3)],     (uint32_t)y1);
                atomicOr(&removed32[2 * (c0 + 3) + 1], (uint32_t)(y1 >> 32));
            }
            const int n0 = __popcll(keep0), n1 = __popcll(keep1);
            const int base = s_kept;               // uniform read (write below is later)
            if ((keep0 >> lane) & 1) {
                int p = __popcll(keep0 & ((1ull << lane) - 1ull));
                s_klist[base + p] = c0 * 64 + lane;
            }
            if ((keep1 >> lane) & 1) {
                int p = n0 + __popcll(keep1 & ((1ull << lane) - 1ull));
                s_klist[base + p] = c1 * 64 + lane;
            }
            if (lane == 0) {
                s_kmask[c0] = keep0;  s_kmask[c1] = keep1;
                s_kbase[c0] = base;   s_kbase[c1] = base + n0;
                int nk      = base + n0 + n1;
                s_kept      = nk;
                s_ksnap[(it + 1) & 1] = nk;        // snapshot for B @ tile it+1
                s_nch       = c1 + 1;
                if (TRYMODE) {
                    if (nk >= MAX_OUT) s_done = 1;
                } else {
                    if (nk >= MAX_OUT || it == NTILE - 1) s_done = 1;
                }
            }
        } else if (wave == 1) {
            // ---- prefetch tile it+1 into pf[buf^1] ----
            const int p0 = 2 * it + 2, p1 = 2 * it + 3;
            const int m0 = 2 * it + 4, m1 = 2 * it + 5;
            if (p0 < NCHUNK) {
                pf[buf ^ 1][0][lane] = maskT[(size_t)p0 * N + p0 * 64 + lane];
                pf[buf ^ 1][1][lane] = maskT[(size_t)p1 * N + p1 * 64 + lane];
                pf[buf ^ 1][2][lane] = maskT[(size_t)p1 * N + p0 * 64 + lane];
                if (m0 < NCHUNK) {
                    pf[buf ^ 1][3][lane] = maskT[(size_t)m0 * N + p0 * 64 + lane];
                    pf[buf ^ 1][4][lane] = maskT[(size_t)m0 * N + p1 * 64 + lane];
                    pf[buf ^ 1][5][lane] = maskT[(size_t)m1 * N + p0 * 64 + lane];
                    pf[buf ^ 1][6][lane] = maskT[(size_t)m1 * N + p1 * 64 + lane];
                }
            }
        } else {
            // ---- lazy B: apply ALL kept rows (tiles <= it-1) to the two
            //      chunks consumed after the next tile: 2it+2, 2it+3 ----
            if (it >= 1) {
                const int kprev = s_ksnap[it & 1]; // kept count before tile it
                const int col   = c0 + 2 + (wave & 1);
                const int idx   = ((wave - 2) >> 1) * 64 + lane;   // 0..447
                uint64_t v = 0;
                if (idx < kprev && col < NCHUNK)
                    v = maskT[(size_t)col * N + s_klist[idx]];
                // wave-wide OR reduce (whole wave has the same col)
                v = wave_or64(v);
                if (lane == 0 && v != 0 && col < NCHUNK) {
                    atomicOr(&removed32[2 * col],     (uint32_t)v);
                    atomicOr(&removed32[2 * col + 1], (uint32_t)(v >> 32));
                }
            }
        }
        __syncthreads();
        if (s_done) break;
    }

    if (TRYMODE) {
        if (t == 0) flag[0] = s_done ? 0 : 1;
        if (!s_done) return;                     // fallback pass will finish
    }

    // ---- parallel output pass ----
    const int nch = s_nch;
    for (int cp = t >> 6; cp < nch; cp += 16) {
        uint64_t km = s_kmask[cp];
        if ((km >> lane) & 1) {
            int pos = s_kbase[cp] + __popcll(km & ((1ull << lane) - 1ull));
            if (pos < MAX_OUT) out[pos] = sidx[cp * 64 + lane];
        }
    }
    const int start = s_kept < MAX_OUT ? s_kept : MAX_OUT;
    for (int p = start + t; p < MAX_OUT; p += 1024) out[p] = -1;
}

// ---------------------------------------------------------------------------
extern "C" void kernel_launch(void* const* d_in, const int* in_sizes, int n_in,
                              void* d_out, int out_size, void* d_ws, size_t ws_size,
                              hipStream_t stream) {
    const float4* rois   = (const float4*)d_in[0];   // [8192,4] fp32
    const float*  scores = (const float*)d_in[1];    // [8192]   fp32
    int* out = (int*)d_out;                          // [300] int32

    // workspace layout (~9.3 MB + flag)
    float4*   sboxes = (float4*)d_ws;                                      // 128 KiB
    int*      sidx   = (int*)((char*)d_ws + 128 * 1024);                   //  32 KiB
    uint64_t* maskT  = (uint64_t*)((char*)d_ws + 160 * 1024);              //   8 MiB
    int*      rank32 = (int*)((char*)d_ws + 160 * 1024 + 8 * 1024 * 1024); //   1 MiB
    int*      flag   = (int*)((char*)d_ws + 160 * 1024 + 9 * 1024 * 1024); //   4 B

    nms_rank_partial<<<dim3(32, 32), dim3(256), 0, stream>>>(scores, rank32);
    nms_scatter<<<dim3(32), dim3(256), 0, stream>>>(rois, rank32, sboxes, sidx);
    nms_mask_pruned<<<dim3(528), dim3(64), 0, stream>>>(sboxes, maskT);
    nms_scan_k<true><<<dim3(1), dim3(1024), 0, stream>>>(maskT, sidx, out, flag);
    // Fallback chain: near-null dispatches when the try-scan completed.
    nms_mask_rest<<<dim3(32, 128), dim3(256), 0, stream>>>(sboxes, maskT, flag);
    nms_scan_k<false><<<dim3(1), dim3(1024), 0, stream>>>(maskT, sidx, out, flag);
}